// Round 21
// baseline (999.088 us; speedup 1.0000x reference)
//
#include <hip/hip_runtime.h>
#include <hip/hip_bf16.h>
#include <math.h>

#define BB   128
#define SS   1500
#define DD   128
#define NHH  4
#define HDD  32
#define FFF  192
#define EPSV 1e-5f
#define GXCH 48

typedef __bf16   bf16x8 __attribute__((ext_vector_type(8)));
typedef float    f32x4  __attribute__((ext_vector_type(4)));
typedef float    f32x2  __attribute__((ext_vector_type(2)));
typedef _Float16 f16x2  __attribute__((ext_vector_type(2)));

// ---------------------------------------------------------------------------
// K_stats (fallback path only): per-token LN1 statistics (mu, rstd).
// ---------------------------------------------------------------------------
__global__ void __launch_bounds__(256) k_stats(
    const int* __restrict__ seq, const float* __restrict__ emb,
    float* __restrict__ stats)
{
    const int w = threadIdx.x >> 6, l = threadIdx.x & 63;
    for (int t = blockIdx.x * 4 + w; t < BB * SS; t += gridDim.x * 4) {
        int tok = seq[t];
        f32x2 v = *(const f32x2*)(emb + (size_t)tok * DD + 2 * l);
        float s1 = v[0] + v[1], s2 = v[0] * v[0] + v[1] * v[1];
        #pragma unroll
        for (int mm = 1; mm <= 32; mm <<= 1) {
            s1 += __shfl_xor(s1, mm);
            s2 += __shfl_xor(s2, mm);
        }
        if (l == 0) {
            float mu  = s1 * (1.f / 128.f);
            float var = s2 * (1.f / 128.f) - mu * mu;
            stats[2 * t]     = mu;
            stats[2 * t + 1] = rsqrtf(var + EPSV);
        }
    }
}

// ---------------------------------------------------------------------------
// K0: transpose + bf16-convert FFN weights; transpose R into per-lane rows.
//   rtA[((h*2+up)*32+e)*32+d] = (up ? Rz : Ri)[h][d][e]
//   rtB[((h*2+up)*32+e)*32+d] = (up ? Ro : Rf)[h][d][e]
// ---------------------------------------------------------------------------
__global__ void k_prep(const float* __restrict__ up, const float* __restrict__ down,
                       const float* __restrict__ Ri, const float* __restrict__ Rf,
                       const float* __restrict__ Rz, const float* __restrict__ Ro,
                       __bf16* __restrict__ wupT, __bf16* __restrict__ wdnT,
                       float* __restrict__ rtA, float* __restrict__ rtB)
{
    int i = blockIdx.x * 256 + threadIdx.x;
    if (i < 384 * 128) {
        int n = i >> 7, k = i & 127;
        wupT[i] = (__bf16)up[k * 384 + n];
    }
    int j = i - 384 * 128;
    if (j >= 0 && j < 128 * 192) {
        int n = j / 192, k = j - n * 192;
        wdnT[j] = (__bf16)down[k * 128 + n];
    }
    int kx = i - (384 * 128 + 128 * 192);
    if (kx >= 0 && kx < 8192) {
        int h = kx >> 11, upq = (kx >> 10) & 1, e = (kx >> 5) & 31, d = kx & 31;
        int src = h * 1024 + d * 32 + e;
        rtA[kx] = upq ? Rz[src] : Ri[src];
        rtB[kx] = upq ? Ro[src] : Rf[src];
    }
}

// ---------------------------------------------------------------------------
// K_gx: y-independent gate pre-activations gx = W*{xc,h} + b, fp16 packed.
// LN1 stats computed in-block. gx dword layout per (b,h,s):
// dword l<32 = (i,f)[e=l]; dword 32+e = (z,o)[e].
// ---------------------------------------------------------------------------
__global__ void __launch_bounds__(256, 2) k_gx(
    const int* __restrict__ seq, const float* __restrict__ emb,
    const float* __restrict__ convw, const float* __restrict__ convb,
    const float* __restrict__ ln1w,
    const float* __restrict__ Wi, const float* __restrict__ Wf,
    const float* __restrict__ Wz, const float* __restrict__ Wo,
    const float* __restrict__ bi, const float* __restrict__ bfv,
    const float* __restrict__ bz, const float* __restrict__ bo,
    unsigned int* __restrict__ gx)
{
    __shared__ float hl[(GXCH + 3) * 128];
    __shared__ float xcl[4 * 32];          // per-wave xc strip

    const int tid = threadIdx.x;
    const int w   = tid >> 6;          // wave = head
    const int l   = tid & 63;
    const int p   = l >> 5;            // gate-of-pair
    const int e   = l & 31;
    const int b   = blockIdx.y;
    const int s0  = blockIdx.x * GXCH;
    const int ch  = w * 32 + e;

    const float* W0 = p ? Wf : Wi;
    const float* W1 = p ? Wo : Wz;
    float wr0[32], wr1[32];
    #pragma unroll
    for (int q = 0; q < 32; ++q) {
        wr0[q] = W0[w * 1024 + e * 32 + q];
        wr1[q] = W1[w * 1024 + e * 32 + q];
    }
    #pragma unroll
    for (int q = 0; q < 32; ++q) {     // pin in VGPRs
        asm volatile("" : "+v"(wr0[q]));
        asm volatile("" : "+v"(wr1[q]));
    }
    const float b0 = (p ? bfv : bi)[w * 32 + e];
    const float b1 = (p ? bo  : bz)[w * 32 + e];
    const float cb = convb[ch];
    float cw[4];
    #pragma unroll
    for (int k = 0; k < 4; ++k) cw[k] = convw[k * DD + ch];
    const float lnw0 = ln1w[2 * l];
    const float lnw1 = ln1w[2 * l + 1];

    // ---- phase 1a: stage RAW emb rows s0-3 .. s0+GXCH-1 into LDS ----
    for (int idx = tid; idx < (GXCH + 3) * 128; idx += 256) {
        int r = idx >> 7, d = idx & 127;
        int sg = s0 - 3 + r;
        float xv = 0.f;
        if (sg >= 0 && sg < SS) {
            int tok = seq[b * SS + sg];
            xv = emb[(size_t)tok * DD + d];
        }
        hl[idx] = xv;
    }
    __syncthreads();

    // ---- phase 1b: per-row LN1 stats + in-place normalize (wave per row) ----
    for (int r = w; r < GXCH + 3; r += 4) {
        float x0 = hl[r * 128 + 2 * l];
        float x1 = hl[r * 128 + 2 * l + 1];
        float s1 = x0 + x1, s2 = x0 * x0 + x1 * x1;
        #pragma unroll
        for (int mm = 1; mm <= 32; mm <<= 1) {
            s1 += __shfl_xor(s1, mm);
            s2 += __shfl_xor(s2, mm);
        }
        float mu  = s1 * (1.f / 128.f);
        float var = s2 * (1.f / 128.f) - mu * mu;
        float rs  = rsqrtf(var + EPSV);
        hl[r * 128 + 2 * l]     = (x0 - mu) * rs * lnw0;
        hl[r * 128 + 2 * l + 1] = (x1 - mu) * rs * lnw1;
    }
    __syncthreads();

    // ---- phase 2: conv+SiLU + per-head projections ----
    for (int t = 0; t < GXCH; ++t) {
        if (s0 + t >= SS) break;                       // uniform exit
        float xc = cb;
        #pragma unroll
        for (int k = 0; k < 4; ++k) xc = fmaf(hl[(t + k) * 128 + ch], cw[k], xc);
        xc = xc * __builtin_amdgcn_rcpf(1.f + __expf(-xc));   // SiLU
        if (l < 32) xcl[w * 32 + e] = xc;              // per-wave strip

        const f32x4* xs = (const f32x4*)(xcl + w * 32);
        const f32x4* hs = (const f32x4*)(hl + (t + 3) * 128 + w * 32);

        float a0 = b0, a1 = 0.f, c0 = b1, c1 = 0.f;
        #pragma unroll
        for (int q8 = 0; q8 < 8; q8 += 2) {
            f32x4 xv0 = xs[q8], xv1 = xs[q8 + 1];
            f32x4 hv0 = hs[q8], hv1 = hs[q8 + 1];
            #pragma unroll
            for (int j = 0; j < 4; ++j) {
                a0 = fmaf(xv0[j], wr0[4 * q8 + j],     a0);
                a1 = fmaf(xv1[j], wr0[4 * q8 + 4 + j], a1);
                c0 = fmaf(hv0[j], wr1[4 * q8 + j],     c0);
                c1 = fmaf(hv1[j], wr1[4 * q8 + 4 + j], c1);
            }
        }
        float a = a0 + a1;            // (i or f) preact
        float cz = c0 + c1;           // (z or o) preact

        float ap = __shfl_xor(a, 32);
        float cp = __shfl_xor(cz, 32);
        if (l < 32) {
            f16x2 w0; w0[0] = (_Float16)a;  w0[1] = (_Float16)ap;   // (i,f)
            f16x2 w1; w1[0] = (_Float16)cz; w1[1] = (_Float16)cp;   // (z,o)
            size_t base = ((size_t)(b * 4 + w) * SS + s0 + t) * 64;
            gx[base + l]      = __builtin_bit_cast(unsigned int, w0);
            gx[base + 32 + l] = __builtin_bit_cast(unsigned int, w1);
        }
    }
}

// ---------------------------------------------------------------------------
// K_scan2: minimal serial scan (proven config: 512 blocks x 64 thr,
// waves_per_eu(1) -> VGPR ~80, R register-resident).
// NEW: cross-half exchange via v_permlane32_swap_b32 (VALU, ~8cy) instead of
// __shfl_xor (DS, ~120cy on the dependent chain). Orientation is verified at
// runtime by swapping the lane index once; a __shfl_xor fallback guards the
// pathological case. Only lanes<32 consume cross values (upper tails are
// don't-care, as before).
// ---------------------------------------------------------------------------
__global__ void __launch_bounds__(64, 1)
__attribute__((amdgpu_waves_per_eu(1)))
k_scan2(
    const unsigned int* __restrict__ gx,
    const float* __restrict__ rtA, const float* __restrict__ rtB,
    _Float16* __restrict__ yout)
{
    const int l  = threadIdx.x;
    const int up = l >> 5;
    const int e  = l & 31;
    const int bh = blockIdx.x;
    const int b  = bh >> 2, h = bh & 3;

    const float* pa = rtA + ((size_t)((h * 2 + up) * 32 + e) * 32);
    const float* pb = rtB + ((size_t)((h * 2 + up) * 32 + e) * 32);
    f32x4 A0 = *(const f32x4*)(pa +  0), A1 = *(const f32x4*)(pa +  4);
    f32x4 A2 = *(const f32x4*)(pa +  8), A3 = *(const f32x4*)(pa + 12);
    f32x4 A4 = *(const f32x4*)(pa + 16), A5 = *(const f32x4*)(pa + 20);
    f32x4 A6 = *(const f32x4*)(pa + 24), A7 = *(const f32x4*)(pa + 28);
    f32x4 B0 = *(const f32x4*)(pb +  0), B1 = *(const f32x4*)(pb +  4);
    f32x4 B2 = *(const f32x4*)(pb +  8), B3 = *(const f32x4*)(pb + 12);
    f32x4 B4 = *(const f32x4*)(pb + 16), B5 = *(const f32x4*)(pb + 20);
    f32x4 B6 = *(const f32x4*)(pb + 24), B7 = *(const f32x4*)(pb + 28);
    // One opaque asm: all 64 R registers simultaneously live + unremat'able.
    asm volatile("" : "+v"(A0), "+v"(A1), "+v"(A2), "+v"(A3),
                      "+v"(A4), "+v"(A5), "+v"(A6), "+v"(A7),
                      "+v"(B0), "+v"(B1), "+v"(B2), "+v"(B3),
                      "+v"(B4), "+v"(B5), "+v"(B6), "+v"(B7));

    // ---- one-time permlane orientation probe (swap the lane index) ----
    // After mov+swap with distinct regs: one operand holds the LOW half
    // broadcast to both halves, the other holds the HIGH half broadcast.
    // Lanes<32 need the HIGH-half value; detect which operand that is.
    float pr0 = (float)l, pr1;
    asm volatile("v_mov_b32 %1, %0\n\tv_permlane32_swap_b32 %0, %1"
                 : "+v"(pr0), "=&v"(pr1));
    float p1l0 = __builtin_bit_cast(float,
                   __builtin_amdgcn_readlane(__builtin_bit_cast(int, pr1), 0));
    float p0l0 = __builtin_bit_cast(float,
                   __builtin_amdgcn_readlane(__builtin_bit_cast(int, pr0), 0));
    const bool plA  = (p1l0 == 32.f);   // second operand = hi-broadcast
    const bool plB  = (p0l0 == 32.f);   // first operand  = hi-broadcast
    const bool plOK = plA || plB;       // wave-uniform

    float y = 0.f, c = 0.f, n = 0.f, m = -1e30f;

    const unsigned int* gp = gx + (size_t)bh * SS * 64 + l;
    _Float16* yp = yout + (size_t)b * SS * DD + h * 32 + e;

    unsigned int pf[4];
    #pragma unroll
    for (int u = 0; u < 4; ++u) pf[u] = gp[(size_t)u * 64];

    for (int s0 = 0; s0 < SS; s0 += 4) {
        #pragma unroll
        for (int u = 0; u < 4; ++u) {
            int s = s0 + u;
            unsigned int gword = pf[u];
            int spf = (s + 4 < SS) ? s + 4 : SS - 1;
            pf[u] = gp[(size_t)spf * 64];

            f16x2 gh = __builtin_bit_cast(f16x2, gword);

            // broadcast y into SGPRs (identical in both halves)
            float yq[32];
            #pragma unroll
            for (int q = 0; q < 32; ++q)
                yq[q] = __builtin_bit_cast(float,
                          __builtin_amdgcn_readlane(__builtin_bit_cast(int, y), q));

            // 4x8 tree-split dual dot products over named f32x4 regs
            float a0 = (float)gh[0], a1 = 0.f, a2 = 0.f, a3 = 0.f;
            float c0 = (float)gh[1], c1 = 0.f, c2 = 0.f, c3 = 0.f;
            #pragma unroll
            for (int j = 0; j < 4; ++j) {
                a0 = fmaf(yq[j],      A0[j], a0);
                a0 = fmaf(yq[4 + j],  A1[j], a0);
                a1 = fmaf(yq[8 + j],  A2[j], a1);
                a1 = fmaf(yq[12 + j], A3[j], a1);
                a2 = fmaf(yq[16 + j], A4[j], a2);
                a2 = fmaf(yq[20 + j], A5[j], a2);
                a3 = fmaf(yq[24 + j], A6[j], a3);
                a3 = fmaf(yq[28 + j], A7[j], a3);
                c0 = fmaf(yq[j],      B0[j], c0);
                c0 = fmaf(yq[4 + j],  B1[j], c0);
                c1 = fmaf(yq[8 + j],  B2[j], c1);
                c1 = fmaf(yq[12 + j], B3[j], c1);
                c2 = fmaf(yq[16 + j], B4[j], c2);
                c2 = fmaf(yq[20 + j], B5[j], c2);
                c3 = fmaf(yq[24 + j], B6[j], c3);
                c3 = fmaf(yq[28 + j], B7[j], c3);
            }
            float accA = (a0 + a1) + (a2 + a3);
            float accB = (c0 + c1) + (c2 + c3);

            // cross-half exchange: lanes<32 need accA/accB from lanes>=32
            float zr, orr;
            if (plOK) {
                float loA = accA, hiA;
                float loB = accB, hiB;
                asm volatile("v_mov_b32 %1, %0\n\tv_permlane32_swap_b32 %0, %1"
                             : "+v"(loA), "=&v"(hiA));
                asm volatile("v_mov_b32 %1, %0\n\tv_permlane32_swap_b32 %0, %1"
                             : "+v"(loB), "=&v"(hiB));
                zr  = plA ? hiA : loA;
                orr = plA ? hiB : loB;
            } else {
                zr  = __shfl_xor(accA, 32);
                orr = __shfl_xor(accB, 32);
            }
            float ir  = accA, fr = accB;        // valid in lanes 0-31

            float lsig = fminf(fr, 0.f) - __logf(1.f + __expf(-fabsf(fr)));
            float lf   = m + lsig;
            float mn   = fmaxf(ir, lf);
            float ig   = __expf(ir - mn);
            float fg   = __expf(lf - mn);
            float e2   = __expf(2.f * zr);
            float zt   = 1.f - 2.f * __builtin_amdgcn_rcpf(e2 + 1.f);
            c = fg * c + ig * zt;
            n = fg * n + ig;
            float so = __builtin_amdgcn_rcpf(1.f + __expf(-orr));
            y = so * c * __builtin_amdgcn_rcpf(n);
            m = mn;

            if (!up) yp[(size_t)s * DD] = (_Float16)y;
        }
    }
}

// ---------------------------------------------------------------------------
// K_scan_fused (fallback, used when ws is too small for gx).
// ---------------------------------------------------------------------------
__global__ void __launch_bounds__(64) k_scan_fused(
    const int* __restrict__ seq, const float* __restrict__ emb,
    const float* __restrict__ stats,
    const float* __restrict__ convw, const float* __restrict__ convb,
    const float* __restrict__ ln1w,
    const float* __restrict__ Wi, const float* __restrict__ Wf,
    const float* __restrict__ Wz, const float* __restrict__ Wo,
    const float* __restrict__ Ri, const float* __restrict__ Rf,
    const float* __restrict__ Rz, const float* __restrict__ Ro,
    const float* __restrict__ bi, const float* __restrict__ bfv,
    const float* __restrict__ bz, const float* __restrict__ bo,
    _Float16* __restrict__ yout)
{
    __shared__ int   stok[SS];
    __shared__ float smu[SS];
    __shared__ float srs[SS];

    const int lane = threadIdx.x;
    const int half = lane >> 5;
    const int e    = lane & 31;
    const int d0   = half * 16;
    const int bh   = blockIdx.x;
    const int b    = bh >> 2, h = bh & 3;
    const int ch   = h * 32 + e;

    for (int i = lane; i < SS; i += 64) {
        stok[i] = seq[b * SS + i];
        f32x2 st = *(const f32x2*)(stats + (size_t)(b * SS + i) * 2);
        smu[i] = st[0];
        srs[i] = st[1];
    }
    __syncthreads();

    float wi[16], wf[16], wz[16], wo[16];
    float ri[16], rf[16], rz[16], ro[16];
    {
        const float* Wib = Wi + h * 1024 + e * 32 + d0;
        const float* Wfb = Wf + h * 1024 + e * 32 + d0;
        const float* Wzb = Wz + h * 1024 + e * 32 + d0;
        const float* Wob = Wo + h * 1024 + e * 32 + d0;
        const float* Rib = Ri + h * 1024 + d0 * 32 + e;
        const float* Rfb = Rf + h * 1024 + d0 * 32 + e;
        const float* Rzb = Rz + h * 1024 + d0 * 32 + e;
        const float* Rob = Ro + h * 1024 + d0 * 32 + e;
        #pragma unroll
        for (int q = 0; q < 16; ++q) {
            wi[q] = Wib[q]; wf[q] = Wfb[q]; wz[q] = Wzb[q]; wo[q] = Wob[q];
            ri[q] = Rib[q * 32]; rf[q] = Rfb[q * 32];
            rz[q] = Rzb[q * 32]; ro[q] = Rob[q * 32];
        }
    }
    const float biv = bi [h * 32 + e];
    const float bfb = bfv[h * 32 + e];
    const float bzv = bz [h * 32 + e];
    const float bov = bo [h * 32 + e];
    const float lnv = ln1w[ch];
    const float cbr = convb[ch];
    const float cw0 = convw[0 * DD + ch], cw1 = convw[1 * DD + ch];
    const float cw2 = convw[2 * DD + ch], cw3 = convw[3 * DD + ch];

    float y = 0.f, c = 0.f, n = 0.f, m = -1e30f;
    float hm1 = 0.f, hm2 = 0.f, hm3 = 0.f;

    _Float16* yp = yout + ((size_t)b * SS) * DD + ch;

    float x0 = emb[(size_t)stok[0] * DD + ch];
    float x1 = (SS > 1) ? emb[(size_t)stok[1] * DD + ch] : 0.f;

    for (int s = 0; s < SS; ++s) {
        float x2 = 0.f;
        if (s + 2 < SS) x2 = emb[(size_t)stok[s + 2] * DD + ch];

        float h0 = (x0 - smu[s]) * srs[s] * lnv;
        float xc = cbr;
        xc = fmaf(hm3, cw0, xc);
        xc = fmaf(hm2, cw1, xc);
        xc = fmaf(hm1, cw2, xc);
        xc = fmaf(h0,  cw3, xc);
        xc = xc / (1.f + __expf(-xc));
        hm3 = hm2; hm2 = hm1; hm1 = h0;

        float ir = 0.f, fr = 0.f, zr = 0.f, orr = 0.f;
        #pragma unroll
        for (int q = 0; q < 16; ++q) {
            float xd = __shfl(xc, d0 + q, 32);
            float hd = __shfl(h0, d0 + q, 32);
            float yd = __shfl(y,  d0 + q, 32);
            ir  = fmaf(xd, wi[q], ir);
            fr  = fmaf(xd, wf[q], fr);
            zr  = fmaf(hd, wz[q], zr);
            orr = fmaf(hd, wo[q], orr);
            ir  = fmaf(yd, ri[q], ir);
            fr  = fmaf(yd, rf[q], fr);
            zr  = fmaf(yd, rz[q], zr);
            orr = fmaf(yd, ro[q], orr);
        }
        ir  += __shfl_xor(ir, 32);
        fr  += __shfl_xor(fr, 32);
        zr  += __shfl_xor(zr, 32);
        orr += __shfl_xor(orr, 32);
        ir += biv; fr += bfb; zr += bzv; orr += bov;

        float lsig = fminf(fr, 0.f) - __logf(1.f + __expf(-fabsf(fr)));
        float lf   = m + lsig;
        float mn   = fmaxf(ir, lf);
        float ig   = __expf(ir - mn);
        float fg   = __expf(lf - mn);
        float e2   = __expf(2.f * zr);
        float zt   = 1.f - 2.f / (e2 + 1.f);
        c = fg * c + ig * zt;
        n = fg * n + ig;
        float so = 1.f / (1.f + __expf(-orr));
        y = so * c / n;
        m = mn;

        if (half == 0) yp[(size_t)s * DD] = (_Float16)y;
        x0 = x1; x1 = x2;
    }
}

// ---------------------------------------------------------------------------
// K3: GroupNorm + residual + LN2 + GEGLU FFN (bf16 MFMA) + post-LN + mean
// pool. 32-token tile per block, 4 waves, 38.4 KB static LDS.
// ---------------------------------------------------------------------------
__global__ void __launch_bounds__(256) k_ffn(
    const int* __restrict__ seq, const float* __restrict__ emb,
    const _Float16* __restrict__ yb, const float* __restrict__ gnw,
    const float* __restrict__ ln2w, const float* __restrict__ lnpw,
    const __bf16* __restrict__ wupT, const __bf16* __restrict__ wdnT,
    float* __restrict__ out)
{
    __shared__ __bf16 h2l[32 * 136];
    __shared__ __bf16 fl [32 * 200];
    __shared__ float  xrl[32 * 132];

    const int tid = threadIdx.x;
    const int w   = tid >> 6, l = tid & 63;
    const int lr  = l & 15,  lh = l >> 4;
    const int b   = blockIdx.y;
    const int t0  = blockIdx.x * 32;

    const float gw0 = gnw[2 * l],  gw1 = gnw[2 * l + 1];
    const float l2w0 = ln2w[2 * l], l2w1 = ln2w[2 * l + 1];
    const float lpw0 = lnpw[2 * l], lpw1 = lnpw[2 * l + 1];

    for (int it = 0; it < 8; ++it) {
        int tt = it * 4 + w;
        int stok = t0 + tt;
        float x0 = 0.f, x1 = 0.f, y0 = 0.f, y1 = 0.f;
        if (stok < SS) {
            int tk = seq[b * SS + stok];
            f32x2 xv = *(const f32x2*)(emb + (size_t)tk * DD + 2 * l);
            f16x2 yv = *(const f16x2*)(yb + ((size_t)b * SS + stok) * DD + 2 * l);
            x0 = xv[0]; x1 = xv[1]; y0 = (float)yv[0]; y1 = (float)yv[1];
        }
        float s1 = y0 + y1, s2 = y0 * y0 + y1 * y1;
        #pragma unroll
        for (int mm = 1; mm <= 8; mm <<= 1) { s1 += __shfl_xor(s1, mm); s2 += __shfl_xor(s2, mm); }
        float mu  = s1 * (1.f / 32.f);
        float var = s2 * (1.f / 32.f) - mu * mu;
        float inv = rsqrtf(var + EPSV);
        float xr0 = x0 + (y0 - mu) * inv * gw0;
        float xr1 = x1 + (y1 - mu) * inv * gw1;
        float t1 = xr0 + xr1, t2 = xr0 * xr0 + xr1 * xr1;
        #pragma unroll
        for (int mm = 1; mm <= 32; mm <<= 1) { t1 += __shfl_xor(t1, mm); t2 += __shfl_xor(t2, mm); }
        float mu2  = t1 * (1.f / 128.f);
        float var2 = t2 * (1.f / 128.f) - mu2 * mu2;
        float inv2 = rsqrtf(var2 + EPSV);
        xrl[tt * 132 + 2 * l]     = xr0;
        xrl[tt * 132 + 2 * l + 1] = xr1;
        h2l[tt * 136 + 2 * l]     = (__bf16)((xr0 - mu2) * inv2 * l2w0);
        h2l[tt * 136 + 2 * l + 1] = (__bf16)((xr1 - mu2) * inv2 * l2w1);
    }
    __syncthreads();

    f32x4 acc1[2][6];
    #pragma unroll
    for (int mt = 0; mt < 2; ++mt)
        #pragma unroll
        for (int nt = 0; nt < 6; ++nt)
            acc1[mt][nt] = (f32x4){0.f, 0.f, 0.f, 0.f};

    #pragma unroll
    for (int kk = 0; kk < 4; ++kk) {
        int k0 = kk * 32;
        bf16x8 bfr[6];
        #pragma unroll
        for (int nt = 0; nt < 6; ++nt) {
            int colbase = (nt < 3) ? (w * 48 + nt * 16) : (192 + w * 48 + (nt - 3) * 16);
            bfr[nt] = *(const bf16x8*)(wupT + (colbase + lr) * DD + k0 + lh * 8);
        }
        #pragma unroll
        for (int mt = 0; mt < 2; ++mt) {
            bf16x8 afr = *(const bf16x8*)(h2l + (mt * 16 + lr) * 136 + k0 + lh * 8);
            #pragma unroll
            for (int nt = 0; nt < 6; ++nt)
                acc1[mt][nt] = __builtin_amdgcn_mfma_f32_16x16x32_bf16(afr, bfr[nt], acc1[mt][nt], 0, 0, 0);
        }
    }

    #pragma unroll
    for (int mt = 0; mt < 2; ++mt)
        #pragma unroll
        for (int nt = 0; nt < 3; ++nt)
            #pragma unroll
            for (int j = 0; j < 4; ++j) {
                int r = mt * 16 + lh * 4 + j;
                int cN = w * 48 + nt * 16 + lr;
                float a  = acc1[mt][nt][j];
                float bv = acc1[mt][nt + 3][j];
                float ge = 0.5f * a * (1.f + erff(a * 0.70710678118f));
                fl[r * 200 + cN] = (__bf16)(ge * bv);
            }
    __syncthreads();

    f32x4 acc2[2][2];
    #pragma unroll
    for (int mt = 0; mt < 2; ++mt) {
        acc2[mt][0] = (f32x4){0.f, 0.f, 0.f, 0.f};
        acc2[mt][1] = (f32x4){0.f, 0.f, 0.f, 0.f};
    }
    #pragma unroll
    for (int kk = 0; kk < 6; ++kk) {
        int k0 = kk * 32;
        bf16x8 bfr2[2];
        #pragma unroll
        for (int nt = 0; nt < 2; ++nt)
            bfr2[nt] = *(const bf16x8*)(wdnT + (w * 32 + nt * 16 + lr) * FFF + k0 + lh * 8);
        #pragma unroll
        for (int mt = 0; mt < 2; ++mt) {
            bf16x8 afr = *(const bf16x8*)(fl + (mt * 16 + lr) * 200 + k0 + lh * 8);
            #pragma unroll
            for (int nt = 0; nt < 2; ++nt)
                acc2[mt][nt] = __builtin_amdgcn_mfma_f32_16x16x32_bf16(afr, bfr2[nt], acc2[mt][nt], 0, 0, 0);
        }
    }
    #pragma unroll
    for (int mt = 0; mt < 2; ++mt)
        #pragma unroll
        for (int nt = 0; nt < 2; ++nt)
            #pragma unroll
            for (int j = 0; j < 4; ++j) {
                int r  = mt * 16 + lh * 4 + j;
                int cN = w * 32 + nt * 16 + lr;
                xrl[r * 132 + cN] += acc2[mt][nt][j];
            }
    __syncthreads();

    float p0 = 0.f, p1 = 0.f;
    for (int it = 0; it < 8; ++it) {
        int tt = it * 4 + w;
        int stok = t0 + tt;
        if (stok >= SS) continue;
        float xr0 = xrl[tt * 132 + 2 * l];
        float xr1 = xrl[tt * 132 + 2 * l + 1];
        float t1 = xr0 + xr1, t2 = xr0 * xr0 + xr1 * xr1;
        #pragma unroll
        for (int mm = 1; mm <= 32; mm <<= 1) { t1 += __shfl_xor(t1, mm); t2 += __shfl_xor(t2, mm); }
        float mu  = t1 * (1.f / 128.f);
        float var = t2 * (1.f / 128.f) - mu * mu;
        float inv = rsqrtf(var + EPSV);
        p0 += (xr0 - mu) * inv * lpw0;
        p1 += (xr1 - mu) * inv * lpw1;
    }
    atomicAdd(out + b * DD + 2 * l,     p0 * (1.f / SS));
    atomicAdd(out + b * DD + 2 * l + 1, p1 * (1.f / SS));
}

// ---------------------------------------------------------------------------
extern "C" void kernel_launch(void* const* d_in, const int* in_sizes, int n_in,
                              void* d_out, int out_size, void* d_ws, size_t ws_size,
                              hipStream_t stream)
{
    const int*   seq   = (const int*)  d_in[0];
    const float* emb   = (const float*)d_in[1];
    const float* convw = (const float*)d_in[2];
    const float* convb = (const float*)d_in[3];
    const float* Wi    = (const float*)d_in[4];
    const float* Wf    = (const float*)d_in[5];
    const float* Wz    = (const float*)d_in[6];
    const float* Wo    = (const float*)d_in[7];
    const float* Ri    = (const float*)d_in[8];
    const float* Rf    = (const float*)d_in[9];
    const float* Rz    = (const float*)d_in[10];
    const float* Ro    = (const float*)d_in[11];
    const float* bi    = (const float*)d_in[12];
    const float* bfp   = (const float*)d_in[13];
    const float* bz    = (const float*)d_in[14];
    const float* bo    = (const float*)d_in[15];
    const float* gnw   = (const float*)d_in[16];
    const float* ln1w  = (const float*)d_in[17];
    const float* ln2w  = (const float*)d_in[18];
    const float* ffup  = (const float*)d_in[19];
    const float* ffdn  = (const float*)d_in[20];
    const float* lnpw  = (const float*)d_in[21];
    float* out = (float*)d_out;

    char* ws = (char*)d_ws;
    float*        stats = (float*)ws;                      //  1,536,000 B (fallback only)
    _Float16*     yws   = (_Float16*)(ws + 1536000);       // 49,152,000 B
    __bf16*       wupT  = (__bf16*)(ws + 50688000);        //     98,304 B
    __bf16*       wdnT  = (__bf16*)(ws + 50786304);        //     49,152 B
    float*        rtA   = (float*)(ws + 50835456);         //     32,768 B
    float*        rtB   = (float*)(ws + 50868224);         //     32,768 B
    unsigned int* gxb   = (unsigned int*)(ws + 50900992);  // 196,608,000 B
    const size_t NEED_GX = 50900992ull + 196608000ull;     // 247,508,992

    hipMemsetAsync(d_out, 0, (size_t)BB * DD * sizeof(float), stream);

    hipLaunchKernelGGL(k_prep, dim3(320), dim3(256), 0, stream,
                       ffup, ffdn, Ri, Rf, Rz, Ro, wupT, wdnT, rtA, rtB);

    if (ws_size >= NEED_GX) {
        hipLaunchKernelGGL(k_gx, dim3((SS + GXCH - 1) / GXCH, BB), dim3(256), 0, stream,
                           seq, emb, convw, convb, ln1w,
                           Wi, Wf, Wz, Wo, bi, bfp, bz, bo, gxb);
        hipLaunchKernelGGL(k_scan2, dim3(512), dim3(64), 0, stream,
                           gxb, rtA, rtB, yws);
    } else {
        hipLaunchKernelGGL(k_stats, dim3(2048), dim3(256), 0, stream, seq, emb, stats);
        hipLaunchKernelGGL(k_scan_fused, dim3(512), dim3(64), 0, stream,
                           seq, emb, stats, convw, convb, ln1w,
                           Wi, Wf, Wz, Wo, Ri, Rf, Rz, Ro, bi, bfp, bz, bo, yws);
    }
    hipLaunchKernelGGL(k_ffn, dim3(47, 128), dim3(256), 0, stream,
                       seq, emb, yws, gnw, ln2w, lnpw, wupT, wdnT, out);
}

// Round 22
// 923.250 us; speedup vs baseline: 1.0821x; 1.0821x over previous
//
#include <hip/hip_runtime.h>
#include <hip/hip_bf16.h>
#include <math.h>

#define BB   128
#define SS   1500
#define DD   128
#define NHH  4
#define HDD  32
#define FFF  192
#define EPSV 1e-5f
#define GXCH 48

typedef __bf16   bf16x8 __attribute__((ext_vector_type(8)));
typedef float    f32x4  __attribute__((ext_vector_type(4)));
typedef float    f32x2  __attribute__((ext_vector_type(2)));
typedef _Float16 f16x2  __attribute__((ext_vector_type(2)));

// ---------------------------------------------------------------------------
// K_stats (fallback path only): per-token LN1 statistics (mu, rstd).
// ---------------------------------------------------------------------------
__global__ void __launch_bounds__(256) k_stats(
    const int* __restrict__ seq, const float* __restrict__ emb,
    float* __restrict__ stats)
{
    const int w = threadIdx.x >> 6, l = threadIdx.x & 63;
    for (int t = blockIdx.x * 4 + w; t < BB * SS; t += gridDim.x * 4) {
        int tok = seq[t];
        f32x2 v = *(const f32x2*)(emb + (size_t)tok * DD + 2 * l);
        float s1 = v[0] + v[1], s2 = v[0] * v[0] + v[1] * v[1];
        #pragma unroll
        for (int mm = 1; mm <= 32; mm <<= 1) {
            s1 += __shfl_xor(s1, mm);
            s2 += __shfl_xor(s2, mm);
        }
        if (l == 0) {
            float mu  = s1 * (1.f / 128.f);
            float var = s2 * (1.f / 128.f) - mu * mu;
            stats[2 * t]     = mu;
            stats[2 * t + 1] = rsqrtf(var + EPSV);
        }
    }
}

// ---------------------------------------------------------------------------
// K0: transpose + bf16-convert FFN weights; transpose R into per-lane rows.
//   rtA[((h*2+up)*32+e)*32+d] = (up ? Rz : Ri)[h][d][e]
//   rtB[((h*2+up)*32+e)*32+d] = (up ? Ro : Rf)[h][d][e]
// ---------------------------------------------------------------------------
__global__ void k_prep(const float* __restrict__ up, const float* __restrict__ down,
                       const float* __restrict__ Ri, const float* __restrict__ Rf,
                       const float* __restrict__ Rz, const float* __restrict__ Ro,
                       __bf16* __restrict__ wupT, __bf16* __restrict__ wdnT,
                       float* __restrict__ rtA, float* __restrict__ rtB)
{
    int i = blockIdx.x * 256 + threadIdx.x;
    if (i < 384 * 128) {
        int n = i >> 7, k = i & 127;
        wupT[i] = (__bf16)up[k * 384 + n];
    }
    int j = i - 384 * 128;
    if (j >= 0 && j < 128 * 192) {
        int n = j / 192, k = j - n * 192;
        wdnT[j] = (__bf16)down[k * 128 + n];
    }
    int kx = i - (384 * 128 + 128 * 192);
    if (kx >= 0 && kx < 8192) {
        int h = kx >> 11, upq = (kx >> 10) & 1, e = (kx >> 5) & 31, d = kx & 31;
        int src = h * 1024 + d * 32 + e;
        rtA[kx] = upq ? Rz[src] : Ri[src];
        rtB[kx] = upq ? Ro[src] : Rf[src];
    }
}

// ---------------------------------------------------------------------------
// K_gx: y-independent gate pre-activations gx = W*{xc,h} + b, fp16 packed.
// LN1 stats computed IN-BLOCK (k_stats fused): phase 1a stages raw emb rows,
// phase 1b does per-row 64-lane reductions + in-place normalize.
// gx dword layout per (b,h,s): dword l<32 = (i,f)[e=l]; dword 32+e = (z,o)[e].
// ---------------------------------------------------------------------------
__global__ void __launch_bounds__(256, 2) k_gx(
    const int* __restrict__ seq, const float* __restrict__ emb,
    const float* __restrict__ convw, const float* __restrict__ convb,
    const float* __restrict__ ln1w,
    const float* __restrict__ Wi, const float* __restrict__ Wf,
    const float* __restrict__ Wz, const float* __restrict__ Wo,
    const float* __restrict__ bi, const float* __restrict__ bfv,
    const float* __restrict__ bz, const float* __restrict__ bo,
    unsigned int* __restrict__ gx)
{
    __shared__ float hl[(GXCH + 3) * 128];
    __shared__ float xcl[4 * 32];          // per-wave xc strip

    const int tid = threadIdx.x;
    const int w   = tid >> 6;          // wave = head
    const int l   = tid & 63;
    const int p   = l >> 5;            // gate-of-pair
    const int e   = l & 31;
    const int b   = blockIdx.y;
    const int s0  = blockIdx.x * GXCH;
    const int ch  = w * 32 + e;

    const float* W0 = p ? Wf : Wi;
    const float* W1 = p ? Wo : Wz;
    float wr0[32], wr1[32];
    #pragma unroll
    for (int q = 0; q < 32; ++q) {
        wr0[q] = W0[w * 1024 + e * 32 + q];
        wr1[q] = W1[w * 1024 + e * 32 + q];
    }
    #pragma unroll
    for (int q = 0; q < 32; ++q) {     // pin in VGPRs
        asm volatile("" : "+v"(wr0[q]));
        asm volatile("" : "+v"(wr1[q]));
    }
    const float b0 = (p ? bfv : bi)[w * 32 + e];
    const float b1 = (p ? bo  : bz)[w * 32 + e];
    const float cb = convb[ch];
    float cw[4];
    #pragma unroll
    for (int k = 0; k < 4; ++k) cw[k] = convw[k * DD + ch];
    const float lnw0 = ln1w[2 * l];
    const float lnw1 = ln1w[2 * l + 1];

    // ---- phase 1a: stage RAW emb rows s0-3 .. s0+GXCH-1 into LDS ----
    for (int idx = tid; idx < (GXCH + 3) * 128; idx += 256) {
        int r = idx >> 7, d = idx & 127;
        int sg = s0 - 3 + r;
        float xv = 0.f;
        if (sg >= 0 && sg < SS) {
            int tok = seq[b * SS + sg];
            xv = emb[(size_t)tok * DD + d];
        }
        hl[idx] = xv;
    }
    __syncthreads();

    // ---- phase 1b: per-row LN1 stats + in-place normalize (wave per row) ----
    for (int r = w; r < GXCH + 3; r += 4) {
        float x0 = hl[r * 128 + 2 * l];
        float x1 = hl[r * 128 + 2 * l + 1];
        float s1 = x0 + x1, s2 = x0 * x0 + x1 * x1;
        #pragma unroll
        for (int mm = 1; mm <= 32; mm <<= 1) {
            s1 += __shfl_xor(s1, mm);
            s2 += __shfl_xor(s2, mm);
        }
        float mu  = s1 * (1.f / 128.f);
        float var = s2 * (1.f / 128.f) - mu * mu;
        float rs  = rsqrtf(var + EPSV);
        hl[r * 128 + 2 * l]     = (x0 - mu) * rs * lnw0;
        hl[r * 128 + 2 * l + 1] = (x1 - mu) * rs * lnw1;
    }
    __syncthreads();

    // ---- phase 2: conv+SiLU + per-head projections ----
    for (int t = 0; t < GXCH; ++t) {
        if (s0 + t >= SS) break;                       // uniform exit
        float xc = cb;
        #pragma unroll
        for (int k = 0; k < 4; ++k) xc = fmaf(hl[(t + k) * 128 + ch], cw[k], xc);
        xc = xc * __builtin_amdgcn_rcpf(1.f + __expf(-xc));   // SiLU
        if (l < 32) xcl[w * 32 + e] = xc;              // per-wave strip

        const f32x4* xs = (const f32x4*)(xcl + w * 32);
        const f32x4* hs = (const f32x4*)(hl + (t + 3) * 128 + w * 32);

        float a0 = b0, a1 = 0.f, c0 = b1, c1 = 0.f;
        #pragma unroll
        for (int q8 = 0; q8 < 8; q8 += 2) {
            f32x4 xv0 = xs[q8], xv1 = xs[q8 + 1];
            f32x4 hv0 = hs[q8], hv1 = hs[q8 + 1];
            #pragma unroll
            for (int j = 0; j < 4; ++j) {
                a0 = fmaf(xv0[j], wr0[4 * q8 + j],     a0);
                a1 = fmaf(xv1[j], wr0[4 * q8 + 4 + j], a1);
                c0 = fmaf(hv0[j], wr1[4 * q8 + j],     c0);
                c1 = fmaf(hv1[j], wr1[4 * q8 + 4 + j], c1);
            }
        }
        float a = a0 + a1;            // (i or f) preact
        float cz = c0 + c1;           // (z or o) preact

        float ap = __shfl_xor(a, 32);
        float cp = __shfl_xor(cz, 32);
        if (l < 32) {
            f16x2 w0; w0[0] = (_Float16)a;  w0[1] = (_Float16)ap;   // (i,f)
            f16x2 w1; w1[0] = (_Float16)cz; w1[1] = (_Float16)cp;   // (z,o)
            size_t base = ((size_t)(b * 4 + w) * SS + s0 + t) * 64;
            gx[base + l]      = __builtin_bit_cast(unsigned int, w0);
            gx[base + 32 + l] = __builtin_bit_cast(unsigned int, w1);
        }
    }
}

// ---------------------------------------------------------------------------
// K_scan2: minimal serial scan (proven config: 512 blocks x 64 thr,
// waves_per_eu(1) -> VGPR 80, R fully register-resident, ~527 us).
// Lanes 0-31: gates (i,f), lanes 32-63: (z,o). y broadcast via v_readlane.
// NOTE: do NOT perturb this body — rounds 9/15-18/21 showed any extra
// register pressure or in-loop asm flips the allocator into spilling R.
// ---------------------------------------------------------------------------
__global__ void __launch_bounds__(64, 1)
__attribute__((amdgpu_waves_per_eu(1)))
k_scan2(
    const unsigned int* __restrict__ gx,
    const float* __restrict__ rtA, const float* __restrict__ rtB,
    _Float16* __restrict__ yout)
{
    const int l  = threadIdx.x;
    const int up = l >> 5;
    const int e  = l & 31;
    const int bh = blockIdx.x;
    const int b  = bh >> 2, h = bh & 3;

    const float* pa = rtA + ((size_t)((h * 2 + up) * 32 + e) * 32);
    const float* pb = rtB + ((size_t)((h * 2 + up) * 32 + e) * 32);
    f32x4 A0 = *(const f32x4*)(pa +  0), A1 = *(const f32x4*)(pa +  4);
    f32x4 A2 = *(const f32x4*)(pa +  8), A3 = *(const f32x4*)(pa + 12);
    f32x4 A4 = *(const f32x4*)(pa + 16), A5 = *(const f32x4*)(pa + 20);
    f32x4 A6 = *(const f32x4*)(pa + 24), A7 = *(const f32x4*)(pa + 28);
    f32x4 B0 = *(const f32x4*)(pb +  0), B1 = *(const f32x4*)(pb +  4);
    f32x4 B2 = *(const f32x4*)(pb +  8), B3 = *(const f32x4*)(pb + 12);
    f32x4 B4 = *(const f32x4*)(pb + 16), B5 = *(const f32x4*)(pb + 20);
    f32x4 B6 = *(const f32x4*)(pb + 24), B7 = *(const f32x4*)(pb + 28);
    // One opaque asm: all 64 R registers simultaneously live + unremat'able.
    asm volatile("" : "+v"(A0), "+v"(A1), "+v"(A2), "+v"(A3),
                      "+v"(A4), "+v"(A5), "+v"(A6), "+v"(A7),
                      "+v"(B0), "+v"(B1), "+v"(B2), "+v"(B3),
                      "+v"(B4), "+v"(B5), "+v"(B6), "+v"(B7));

    float y = 0.f, c = 0.f, n = 0.f, m = -1e30f;

    const unsigned int* gp = gx + (size_t)bh * SS * 64 + l;
    _Float16* yp = yout + (size_t)b * SS * DD + h * 32 + e;

    unsigned int pf[4];
    #pragma unroll
    for (int u = 0; u < 4; ++u) pf[u] = gp[(size_t)u * 64];

    for (int s0 = 0; s0 < SS; s0 += 4) {
        #pragma unroll
        for (int u = 0; u < 4; ++u) {
            int s = s0 + u;
            unsigned int gword = pf[u];
            int spf = (s + 4 < SS) ? s + 4 : SS - 1;
            pf[u] = gp[(size_t)spf * 64];

            f16x2 gh = __builtin_bit_cast(f16x2, gword);

            // broadcast y into SGPRs (identical in both halves)
            float yq[32];
            #pragma unroll
            for (int q = 0; q < 32; ++q)
                yq[q] = __builtin_bit_cast(float,
                          __builtin_amdgcn_readlane(__builtin_bit_cast(int, y), q));

            // 4x8 tree-split dual dot products over named f32x4 regs
            float a0 = (float)gh[0], a1 = 0.f, a2 = 0.f, a3 = 0.f;
            float c0 = (float)gh[1], c1 = 0.f, c2 = 0.f, c3 = 0.f;
            #pragma unroll
            for (int j = 0; j < 4; ++j) {
                a0 = fmaf(yq[j],      A0[j], a0);
                a0 = fmaf(yq[4 + j],  A1[j], a0);
                a1 = fmaf(yq[8 + j],  A2[j], a1);
                a1 = fmaf(yq[12 + j], A3[j], a1);
                a2 = fmaf(yq[16 + j], A4[j], a2);
                a2 = fmaf(yq[20 + j], A5[j], a2);
                a3 = fmaf(yq[24 + j], A6[j], a3);
                a3 = fmaf(yq[28 + j], A7[j], a3);
                c0 = fmaf(yq[j],      B0[j], c0);
                c0 = fmaf(yq[4 + j],  B1[j], c0);
                c1 = fmaf(yq[8 + j],  B2[j], c1);
                c1 = fmaf(yq[12 + j], B3[j], c1);
                c2 = fmaf(yq[16 + j], B4[j], c2);
                c2 = fmaf(yq[20 + j], B5[j], c2);
                c3 = fmaf(yq[24 + j], B6[j], c3);
                c3 = fmaf(yq[28 + j], B7[j], c3);
            }
            float accA = (a0 + a1) + (a2 + a3);
            float accB = (c0 + c1) + (c2 + c3);

            float zr  = __shfl_xor(accA, 32);   // lower lanes get z preact
            float orr = __shfl_xor(accB, 32);   // lower lanes get o preact
            float ir  = accA, fr = accB;        // valid in lanes 0-31

            float lsig = fminf(fr, 0.f) - __logf(1.f + __expf(-fabsf(fr)));
            float lf   = m + lsig;
            float mn   = fmaxf(ir, lf);
            float ig   = __expf(ir - mn);
            float fg   = __expf(lf - mn);
            float e2   = __expf(2.f * zr);
            float zt   = 1.f - 2.f * __builtin_amdgcn_rcpf(e2 + 1.f);
            c = fg * c + ig * zt;
            n = fg * n + ig;
            float so = __builtin_amdgcn_rcpf(1.f + __expf(-orr));
            y = so * c * __builtin_amdgcn_rcpf(n);
            m = mn;

            if (!up) yp[(size_t)s * DD] = (_Float16)y;
        }
    }
}

// ---------------------------------------------------------------------------
// K_scan_fused (fallback, used when ws is too small for gx).
// ---------------------------------------------------------------------------
__global__ void __launch_bounds__(64) k_scan_fused(
    const int* __restrict__ seq, const float* __restrict__ emb,
    const float* __restrict__ stats,
    const float* __restrict__ convw, const float* __restrict__ convb,
    const float* __restrict__ ln1w,
    const float* __restrict__ Wi, const float* __restrict__ Wf,
    const float* __restrict__ Wz, const float* __restrict__ Wo,
    const float* __restrict__ Ri, const float* __restrict__ Rf,
    const float* __restrict__ Rz, const float* __restrict__ Ro,
    const float* __restrict__ bi, const float* __restrict__ bfv,
    const float* __restrict__ bz, const float* __restrict__ bo,
    _Float16* __restrict__ yout)
{
    __shared__ int   stok[SS];
    __shared__ float smu[SS];
    __shared__ float srs[SS];

    const int lane = threadIdx.x;
    const int half = lane >> 5;
    const int e    = lane & 31;
    const int d0   = half * 16;
    const int bh   = blockIdx.x;
    const int b    = bh >> 2, h = bh & 3;
    const int ch   = h * 32 + e;

    for (int i = lane; i < SS; i += 64) {
        stok[i] = seq[b * SS + i];
        f32x2 st = *(const f32x2*)(stats + (size_t)(b * SS + i) * 2);
        smu[i] = st[0];
        srs[i] = st[1];
    }
    __syncthreads();

    float wi[16], wf[16], wz[16], wo[16];
    float ri[16], rf[16], rz[16], ro[16];
    {
        const float* Wib = Wi + h * 1024 + e * 32 + d0;
        const float* Wfb = Wf + h * 1024 + e * 32 + d0;
        const float* Wzb = Wz + h * 1024 + e * 32 + d0;
        const float* Wob = Wo + h * 1024 + e * 32 + d0;
        const float* Rib = Ri + h * 1024 + d0 * 32 + e;
        const float* Rfb = Rf + h * 1024 + d0 * 32 + e;
        const float* Rzb = Rz + h * 1024 + d0 * 32 + e;
        const float* Rob = Ro + h * 1024 + d0 * 32 + e;
        #pragma unroll
        for (int q = 0; q < 16; ++q) {
            wi[q] = Wib[q]; wf[q] = Wfb[q]; wz[q] = Wzb[q]; wo[q] = Wob[q];
            ri[q] = Rib[q * 32]; rf[q] = Rfb[q * 32];
            rz[q] = Rzb[q * 32]; ro[q] = Rob[q * 32];
        }
    }
    const float biv = bi [h * 32 + e];
    const float bfb = bfv[h * 32 + e];
    const float bzv = bz [h * 32 + e];
    const float bov = bo [h * 32 + e];
    const float lnv = ln1w[ch];
    const float cbr = convb[ch];
    const float cw0 = convw[0 * DD + ch], cw1 = convw[1 * DD + ch];
    const float cw2 = convw[2 * DD + ch], cw3 = convw[3 * DD + ch];

    float y = 0.f, c = 0.f, n = 0.f, m = -1e30f;
    float hm1 = 0.f, hm2 = 0.f, hm3 = 0.f;

    _Float16* yp = yout + ((size_t)b * SS) * DD + ch;

    float x0 = emb[(size_t)stok[0] * DD + ch];
    float x1 = (SS > 1) ? emb[(size_t)stok[1] * DD + ch] : 0.f;

    for (int s = 0; s < SS; ++s) {
        float x2 = 0.f;
        if (s + 2 < SS) x2 = emb[(size_t)stok[s + 2] * DD + ch];

        float h0 = (x0 - smu[s]) * srs[s] * lnv;
        float xc = cbr;
        xc = fmaf(hm3, cw0, xc);
        xc = fmaf(hm2, cw1, xc);
        xc = fmaf(hm1, cw2, xc);
        xc = fmaf(h0,  cw3, xc);
        xc = xc / (1.f + __expf(-xc));
        hm3 = hm2; hm2 = hm1; hm1 = h0;

        float ir = 0.f, fr = 0.f, zr = 0.f, orr = 0.f;
        #pragma unroll
        for (int q = 0; q < 16; ++q) {
            float xd = __shfl(xc, d0 + q, 32);
            float hd = __shfl(h0, d0 + q, 32);
            float yd = __shfl(y,  d0 + q, 32);
            ir  = fmaf(xd, wi[q], ir);
            fr  = fmaf(xd, wf[q], fr);
            zr  = fmaf(hd, wz[q], zr);
            orr = fmaf(hd, wo[q], orr);
            ir  = fmaf(yd, ri[q], ir);
            fr  = fmaf(yd, rf[q], fr);
            zr  = fmaf(yd, rz[q], zr);
            orr = fmaf(yd, ro[q], orr);
        }
        ir  += __shfl_xor(ir, 32);
        fr  += __shfl_xor(fr, 32);
        zr  += __shfl_xor(zr, 32);
        orr += __shfl_xor(orr, 32);
        ir += biv; fr += bfb; zr += bzv; orr += bov;

        float lsig = fminf(fr, 0.f) - __logf(1.f + __expf(-fabsf(fr)));
        float lf   = m + lsig;
        float mn   = fmaxf(ir, lf);
        float ig   = __expf(ir - mn);
        float fg   = __expf(lf - mn);
        float e2   = __expf(2.f * zr);
        float zt   = 1.f - 2.f / (e2 + 1.f);
        c = fg * c + ig * zt;
        n = fg * n + ig;
        float so = 1.f / (1.f + __expf(-orr));
        y = so * c / n;
        m = mn;

        if (half == 0) yp[(size_t)s * DD] = (_Float16)y;
        x0 = x1; x1 = x2;
    }
}

// ---------------------------------------------------------------------------
// K3: GroupNorm + residual + LN2 + GEGLU FFN (bf16 MFMA) + post-LN + mean
// pool. 32-token tile per block, 4 waves, 38.4 KB static LDS.
// ---------------------------------------------------------------------------
__global__ void __launch_bounds__(256) k_ffn(
    const int* __restrict__ seq, const float* __restrict__ emb,
    const _Float16* __restrict__ yb, const float* __restrict__ gnw,
    const float* __restrict__ ln2w, const float* __restrict__ lnpw,
    const __bf16* __restrict__ wupT, const __bf16* __restrict__ wdnT,
    float* __restrict__ out)
{
    __shared__ __bf16 h2l[32 * 136];
    __shared__ __bf16 fl [32 * 200];
    __shared__ float  xrl[32 * 132];

    const int tid = threadIdx.x;
    const int w   = tid >> 6, l = tid & 63;
    const int lr  = l & 15,  lh = l >> 4;
    const int b   = blockIdx.y;
    const int t0  = blockIdx.x * 32;

    const float gw0 = gnw[2 * l],  gw1 = gnw[2 * l + 1];
    const float l2w0 = ln2w[2 * l], l2w1 = ln2w[2 * l + 1];
    const float lpw0 = lnpw[2 * l], lpw1 = lnpw[2 * l + 1];

    for (int it = 0; it < 8; ++it) {
        int tt = it * 4 + w;
        int stok = t0 + tt;
        float x0 = 0.f, x1 = 0.f, y0 = 0.f, y1 = 0.f;
        if (stok < SS) {
            int tk = seq[b * SS + stok];
            f32x2 xv = *(const f32x2*)(emb + (size_t)tk * DD + 2 * l);
            f16x2 yv = *(const f16x2*)(yb + ((size_t)b * SS + stok) * DD + 2 * l);
            x0 = xv[0]; x1 = xv[1]; y0 = (float)yv[0]; y1 = (float)yv[1];
        }
        float s1 = y0 + y1, s2 = y0 * y0 + y1 * y1;
        #pragma unroll
        for (int mm = 1; mm <= 8; mm <<= 1) { s1 += __shfl_xor(s1, mm); s2 += __shfl_xor(s2, mm); }
        float mu  = s1 * (1.f / 32.f);
        float var = s2 * (1.f / 32.f) - mu * mu;
        float inv = rsqrtf(var + EPSV);
        float xr0 = x0 + (y0 - mu) * inv * gw0;
        float xr1 = x1 + (y1 - mu) * inv * gw1;
        float t1 = xr0 + xr1, t2 = xr0 * xr0 + xr1 * xr1;
        #pragma unroll
        for (int mm = 1; mm <= 32; mm <<= 1) { t1 += __shfl_xor(t1, mm); t2 += __shfl_xor(t2, mm); }
        float mu2  = t1 * (1.f / 128.f);
        float var2 = t2 * (1.f / 128.f) - mu2 * mu2;
        float inv2 = rsqrtf(var2 + EPSV);
        xrl[tt * 132 + 2 * l]     = xr0;
        xrl[tt * 132 + 2 * l + 1] = xr1;
        h2l[tt * 136 + 2 * l]     = (__bf16)((xr0 - mu2) * inv2 * l2w0);
        h2l[tt * 136 + 2 * l + 1] = (__bf16)((xr1 - mu2) * inv2 * l2w1);
    }
    __syncthreads();

    f32x4 acc1[2][6];
    #pragma unroll
    for (int mt = 0; mt < 2; ++mt)
        #pragma unroll
        for (int nt = 0; nt < 6; ++nt)
            acc1[mt][nt] = (f32x4){0.f, 0.f, 0.f, 0.f};

    #pragma unroll
    for (int kk = 0; kk < 4; ++kk) {
        int k0 = kk * 32;
        bf16x8 bfr[6];
        #pragma unroll
        for (int nt = 0; nt < 6; ++nt) {
            int colbase = (nt < 3) ? (w * 48 + nt * 16) : (192 + w * 48 + (nt - 3) * 16);
            bfr[nt] = *(const bf16x8*)(wupT + (colbase + lr) * DD + k0 + lh * 8);
        }
        #pragma unroll
        for (int mt = 0; mt < 2; ++mt) {
            bf16x8 afr = *(const bf16x8*)(h2l + (mt * 16 + lr) * 136 + k0 + lh * 8);
            #pragma unroll
            for (int nt = 0; nt < 6; ++nt)
                acc1[mt][nt] = __builtin_amdgcn_mfma_f32_16x16x32_bf16(afr, bfr[nt], acc1[mt][nt], 0, 0, 0);
        }
    }

    #pragma unroll
    for (int mt = 0; mt < 2; ++mt)
        #pragma unroll
        for (int nt = 0; nt < 3; ++nt)
            #pragma unroll
            for (int j = 0; j < 4; ++j) {
                int r = mt * 16 + lh * 4 + j;
                int cN = w * 48 + nt * 16 + lr;
                float a  = acc1[mt][nt][j];
                float bv = acc1[mt][nt + 3][j];
                float ge = 0.5f * a * (1.f + erff(a * 0.70710678118f));
                fl[r * 200 + cN] = (__bf16)(ge * bv);
            }
    __syncthreads();

    f32x4 acc2[2][2];
    #pragma unroll
    for (int mt = 0; mt < 2; ++mt) {
        acc2[mt][0] = (f32x4){0.f, 0.f, 0.f, 0.f};
        acc2[mt][1] = (f32x4){0.f, 0.f, 0.f, 0.f};
    }
    #pragma unroll
    for (int kk = 0; kk < 6; ++kk) {
        int k0 = kk * 32;
        bf16x8 bfr2[2];
        #pragma unroll
        for (int nt = 0; nt < 2; ++nt)
            bfr2[nt] = *(const bf16x8*)(wdnT + (w * 32 + nt * 16 + lr) * FFF + k0 + lh * 8);
        #pragma unroll
        for (int mt = 0; mt < 2; ++mt) {
            bf16x8 afr = *(const bf16x8*)(fl + (mt * 16 + lr) * 200 + k0 + lh * 8);
            #pragma unroll
            for (int nt = 0; nt < 2; ++nt)
                acc2[mt][nt] = __builtin_amdgcn_mfma_f32_16x16x32_bf16(afr, bfr2[nt], acc2[mt][nt], 0, 0, 0);
        }
    }
    #pragma unroll
    for (int mt = 0; mt < 2; ++mt)
        #pragma unroll
        for (int nt = 0; nt < 2; ++nt)
            #pragma unroll
            for (int j = 0; j < 4; ++j) {
                int r  = mt * 16 + lh * 4 + j;
                int cN = w * 32 + nt * 16 + lr;
                xrl[r * 132 + cN] += acc2[mt][nt][j];
            }
    __syncthreads();

    float p0 = 0.f, p1 = 0.f;
    for (int it = 0; it < 8; ++it) {
        int tt = it * 4 + w;
        int stok = t0 + tt;
        if (stok >= SS) continue;
        float xr0 = xrl[tt * 132 + 2 * l];
        float xr1 = xrl[tt * 132 + 2 * l + 1];
        float t1 = xr0 + xr1, t2 = xr0 * xr0 + xr1 * xr1;
        #pragma unroll
        for (int mm = 1; mm <= 32; mm <<= 1) { t1 += __shfl_xor(t1, mm); t2 += __shfl_xor(t2, mm); }
        float mu  = t1 * (1.f / 128.f);
        float var = t2 * (1.f / 128.f) - mu * mu;
        float inv = rsqrtf(var + EPSV);
        p0 += (xr0 - mu) * inv * lpw0;
        p1 += (xr1 - mu) * inv * lpw1;
    }
    atomicAdd(out + b * DD + 2 * l,     p0 * (1.f / SS));
    atomicAdd(out + b * DD + 2 * l + 1, p1 * (1.f / SS));
}

// ---------------------------------------------------------------------------
extern "C" void kernel_launch(void* const* d_in, const int* in_sizes, int n_in,
                              void* d_out, int out_size, void* d_ws, size_t ws_size,
                              hipStream_t stream)
{
    const int*   seq   = (const int*)  d_in[0];
    const float* emb   = (const float*)d_in[1];
    const float* convw = (const float*)d_in[2];
    const float* convb = (const float*)d_in[3];
    const float* Wi    = (const float*)d_in[4];
    const float* Wf    = (const float*)d_in[5];
    const float* Wz    = (const float*)d_in[6];
    const float* Wo    = (const float*)d_in[7];
    const float* Ri    = (const float*)d_in[8];
    const float* Rf    = (const float*)d_in[9];
    const float* Rz    = (const float*)d_in[10];
    const float* Ro    = (const float*)d_in[11];
    const float* bi    = (const float*)d_in[12];
    const float* bfp   = (const float*)d_in[13];
    const float* bz    = (const float*)d_in[14];
    const float* bo    = (const float*)d_in[15];
    const float* gnw   = (const float*)d_in[16];
    const float* ln1w  = (const float*)d_in[17];
    const float* ln2w  = (const float*)d_in[18];
    const float* ffup  = (const float*)d_in[19];
    const float* ffdn  = (const float*)d_in[20];
    const float* lnpw  = (const float*)d_in[21];
    float* out = (float*)d_out;

    char* ws = (char*)d_ws;
    float*        stats = (float*)ws;                      //  1,536,000 B (fallback only)
    _Float16*     yws   = (_Float16*)(ws + 1536000);       // 49,152,000 B
    __bf16*       wupT  = (__bf16*)(ws + 50688000);        //     98,304 B
    __bf16*       wdnT  = (__bf16*)(ws + 50786304);        //     49,152 B
    float*        rtA   = (float*)(ws + 50835456);         //     32,768 B
    float*        rtB   = (float*)(ws + 50868224);         //     32,768 B
    unsigned int* gxb   = (unsigned int*)(ws + 50900992);  // 196,608,000 B
    const size_t NEED_GX = 50900992ull + 196608000ull;     // 247,508,992

    hipMemsetAsync(d_out, 0, (size_t)BB * DD * sizeof(float), stream);

    hipLaunchKernelGGL(k_prep, dim3(320), dim3(256), 0, stream,
                       ffup, ffdn, Ri, Rf, Rz, Ro, wupT, wdnT, rtA, rtB);

    if (ws_size >= NEED_GX) {
        hipLaunchKernelGGL(k_gx, dim3((SS + GXCH - 1) / GXCH, BB), dim3(256), 0, stream,
                           seq, emb, convw, convb, ln1w,
                           Wi, Wf, Wz, Wo, bi, bfp, bz, bo, gxb);
        hipLaunchKernelGGL(k_scan2, dim3(512), dim3(64), 0, stream,
                           gxb, rtA, rtB, yws);
    } else {
        hipLaunchKernelGGL(k_stats, dim3(2048), dim3(256), 0, stream, seq, emb, stats);
        hipLaunchKernelGGL(k_scan_fused, dim3(512), dim3(64), 0, stream,
                           seq, emb, stats, convw, convb, ln1w,
                           Wi, Wf, Wz, Wo, Ri, Rf, Rz, Ro, bi, bfp, bz, bo, yws);
    }
    hipLaunchKernelGGL(k_ffn, dim3(47, 128), dim3(256), 0, stream,
                       seq, emb, yws, gnw, ln2w, lnpw, wupT, wdnT, out);
}